// Round 7
// baseline (46.133 us; speedup 1.0000x reference)
//
#include <hip/hip_runtime.h>
#include <hip/hip_bf16.h>

#define TT 2048
#define HH 1024
#define NTAGS 74
#define NPAD 80
#define CHK 64            // K elements per chunk
#define NCH (HH / CHK)    // 16 chunks
#define MROWS 64          // rows per block
#define THREADS 256

typedef __bf16 bf16x8 __attribute__((ext_vector_type(8)));
typedef __bf16 bf16x4 __attribute__((ext_vector_type(4)));
typedef float f32x4 __attribute__((ext_vector_type(4)));

// Transpose + convert W_out [1024][74] f32 -> Wt [80][1024] bf16 (pad cols 74..79 = 0)
__global__ __launch_bounds__(256) void prep_w_kernel(const float* __restrict__ W,
                                                     __bf16* __restrict__ Wt) {
    __shared__ float tile[64][80];
    const int k0 = blockIdx.x * 64;
    const int tid = threadIdx.x;
    for (int i = tid; i < 64 * NTAGS; i += 256) {
        int k = i / NTAGS, n = i - k * NTAGS;
        tile[k][n] = W[(k0 + k) * NTAGS + n];
    }
    __syncthreads();
    for (int i = tid; i < NPAD * 64; i += 256) {
        int n = i >> 6, kk = i & 63;
        float v = (n < NTAGS) ? tile[kk][n] : 0.0f;
        Wt[n * HH + k0 + kk] = (__bf16)v;
    }
}

// Fused gather-blend + skinny GEMM [B*T,1024]x[1024,74] via 16x16x32 bf16 MFMA.
// Block = 256 thr (4 waves), M=64 rows, grid 512 (2 blocks/CU).
// COALESCED A staging: pass p covers row=(tid+256p)>>4, unit=(tid+256p)&15 ->
// 16 lanes read 256 B contiguous per row; one instruction = 4 rows x 256 B =
// 8-cache-line minimum. K chunks of 64; A dbuf (2x8KB) + W dbuf (2x10KB) LDS,
// XOR-swizzled (byte ^= (row&7)<<4). Loop: commit regs(ch+1) -> issue
// loads(ch+2) -> MFMA(ch) -> barrier. Fully-invalid blocks early-exit (bias).
__global__ __launch_bounds__(256, 2) void slu_main(const float* __restrict__ out_char,
                                                   const float* __restrict__ out_word,
                                                   const int* __restrict__ word_idx,
                                                   const int* __restrict__ is_head,
                                                   const int* __restrict__ valid_mask,
                                                   const __bf16* __restrict__ Wt,
                                                   const float* __restrict__ b_out,
                                                   float* __restrict__ out) {
    // LDS: A[2] @ 0 (2*8192), W[2] @ 16384 (2*10240) = 36864 B
    __shared__ __align__(16) char smem[36864];
    const int tid = threadIdx.x;
    const int wv = tid >> 6;
    const int lane = tid & 63;
    const int l15 = lane & 15;
    const int kgrp = lane >> 4;
    const int rowbase = blockIdx.x * MROWS;
    const int batch = rowbase >> 11;  // T = 2048, 64 | 2048

    // ---- A staging: 4 passes; pass p: row=(tid+256p)>>4, 16B f32 unit=(tid+256p)&15 ----
    const float* acp[4];
    const float* awp[4];
    float arate[4], acrate[4];
    int aval[4], aoff[4];
#pragma unroll
    for (int p = 0; p < 4; ++p) {
        const int u = tid + 256 * p;
        const int row = u >> 4;   // 0..63
        const int k16 = u & 15;   // 16B unit within the 256B f32 chunk-row
        const int r = rowbase + row;
        const int widx = word_idx[r];
        const int v = valid_mask[r];
        const float rt = is_head[r] ? 0.88f : 0.70f;
        arate[p] = v ? rt : 0.0f;
        acrate[p] = v ? (1.0f - rt) : 0.0f;
        aval[p] = v;
        acp[p] = out_char + (size_t)r * HH + k16 * 4;
        awp[p] = out_word + ((size_t)batch * TT + widx) * HH + k16 * 4;
        aoff[p] = (row * 128 + k16 * 8) ^ ((row & 7) << 4);
    }

    // ---- fully-invalid block: write bias rows, skip the K loop ----
    const int anyv = aval[0] | aval[1] | aval[2] | aval[3];
    if (!__syncthreads_or(anyv)) {
        for (int i = tid; i < MROWS * NTAGS; i += THREADS) {
            const int rr = i / NTAGS, cc = i - rr * NTAGS;
            out[(size_t)(rowbase + rr) * NTAGS + cc] = b_out[cc];
        }
        return;
    }

    // ---- W staging: 640 16B-units/chunk; thread covers tid, tid+256, (tid<128)?tid+512 ----
    const int wn0 = tid >> 3, wsb = tid & 7;
    const __bf16* wgp0 = Wt + (size_t)wn0 * HH + wsb * 8;
    const __bf16* wgp1 = wgp0 + 32 * HH;
    const __bf16* wgp2 = wgp0 + 64 * HH;
    const int wsw = (wn0 & 7) << 4;
    const int wwr0 = (wn0 * 128 + wsb * 16) ^ wsw;
    const int wwr1 = ((wn0 + 32) * 128 + wsb * 16) ^ wsw;
    const int wwr2 = ((wn0 + 64) * 128 + wsb * 16) ^ wsw;
    const bool w3 = (tid < 128);

    // ---- fragment read offsets (swizzle matches writes; arow&7 == l15&7) ----
    const int fsw = (l15 & 7) << 4;
    const int arow = wv * 16 + l15;
    int afr[2], wfr[2][5];
#pragma unroll
    for (int s = 0; s < 2; ++s) {
        afr[s] = (arow * 128 + s * 64 + kgrp * 16) ^ fsw;
#pragma unroll
        for (int nt = 0; nt < 5; ++nt)
            wfr[s][nt] = ((nt * 16 + l15) * 128 + s * 64 + kgrp * 16) ^ fsw;
    }

    f32x4 acc[5];
#pragma unroll
    for (int nt = 0; nt < 5; ++nt) acc[nt] = (f32x4){0.f, 0.f, 0.f, 0.f};

    float4 ac[4], aw[4];   // held A loads (chunk ch+2), one float4 per pass
    bf16x8 wreg0, wreg1, wreg2;

    // ---- prologue: stage chunk 0 into buf 0; prefetch chunk 1 into regs ----
    {
        float4 c0[4], w0[4];
#pragma unroll
        for (int p = 0; p < 4; ++p) {
            if (aval[p]) {
                c0[p] = *(const float4*)(acp[p]);
                w0[p] = *(const float4*)(awp[p]);
            }
        }
        bf16x8 wr0 = *(const bf16x8*)(wgp0);
        bf16x8 wr1 = *(const bf16x8*)(wgp1);
        bf16x8 wr2 = w3 ? *(const bf16x8*)(wgp2) : (bf16x8)0;
#pragma unroll
        for (int p = 0; p < 4; ++p) {
            bf16x4 f;
            if (aval[p]) {
                f[0] = (__bf16)(w0[p].x * arate[p] + c0[p].x * acrate[p]);
                f[1] = (__bf16)(w0[p].y * arate[p] + c0[p].y * acrate[p]);
                f[2] = (__bf16)(w0[p].z * arate[p] + c0[p].z * acrate[p]);
                f[3] = (__bf16)(w0[p].w * arate[p] + c0[p].w * acrate[p]);
            } else {
                f[0] = f[1] = f[2] = f[3] = (__bf16)0.0f;
            }
            *(bf16x4*)(smem + aoff[p]) = f;
        }
        *(bf16x8*)(smem + 16384 + wwr0) = wr0;
        *(bf16x8*)(smem + 16384 + wwr1) = wr1;
        if (w3) *(bf16x8*)(smem + 16384 + wwr2) = wr2;
        // prefetch chunk 1 into regs
#pragma unroll
        for (int p = 0; p < 4; ++p) {
            if (aval[p]) {
                ac[p] = *(const float4*)(acp[p] + CHK);
                aw[p] = *(const float4*)(awp[p] + CHK);
            }
        }
        wreg0 = *(const bf16x8*)(wgp0 + CHK);
        wreg1 = *(const bf16x8*)(wgp1 + CHK);
        wreg2 = w3 ? *(const bf16x8*)(wgp2 + CHK) : (bf16x8)0;
    }
    __syncthreads();

    // ---- main loop ----
    for (int ch = 0; ch < NCH; ++ch) {
        // 1) commit prefetched chunk ch+1 to the other buffer
        if (ch + 1 < NCH) {
            char* An = smem + ((ch + 1) & 1) * 8192;
            char* Wn = smem + 16384 + ((ch + 1) & 1) * 10240;
#pragma unroll
            for (int p = 0; p < 4; ++p) {
                bf16x4 f;
                if (aval[p]) {
                    f[0] = (__bf16)(aw[p].x * arate[p] + ac[p].x * acrate[p]);
                    f[1] = (__bf16)(aw[p].y * arate[p] + ac[p].y * acrate[p]);
                    f[2] = (__bf16)(aw[p].z * arate[p] + ac[p].z * acrate[p]);
                    f[3] = (__bf16)(aw[p].w * arate[p] + ac[p].w * acrate[p]);
                } else {
                    f[0] = f[1] = f[2] = f[3] = (__bf16)0.0f;
                }
                *(bf16x4*)(An + aoff[p]) = f;
            }
            *(bf16x8*)(Wn + wwr0) = wreg0;
            *(bf16x8*)(Wn + wwr1) = wreg1;
            if (w3) *(bf16x8*)(Wn + wwr2) = wreg2;
        }
        // 2) issue global loads for chunk ch+2 (held in regs across compute)
        if (ch + 2 < NCH) {
            const int ko = (ch + 2) * CHK;
#pragma unroll
            for (int p = 0; p < 4; ++p) {
                if (aval[p]) {
                    ac[p] = *(const float4*)(acp[p] + ko);
                    aw[p] = *(const float4*)(awp[p] + ko);
                }
            }
            wreg0 = *(const bf16x8*)(wgp0 + ko);
            wreg1 = *(const bf16x8*)(wgp1 + ko);
            wreg2 = w3 ? *(const bf16x8*)(wgp2 + ko) : (bf16x8)0;
        }
        // 3) compute chunk ch
        const char* Ab = smem + (ch & 1) * 8192;
        const char* Wb = smem + 16384 + (ch & 1) * 10240;
#pragma unroll
        for (int s = 0; s < 2; ++s) {
            bf16x8 a = *(const bf16x8*)(Ab + afr[s]);
#pragma unroll
            for (int nt = 0; nt < 5; ++nt) {
                bf16x8 bw = *(const bf16x8*)(Wb + wfr[s][nt]);
                acc[nt] = __builtin_amdgcn_mfma_f32_16x16x32_bf16(a, bw, acc[nt], 0, 0, 0);
            }
        }
        __syncthreads();
    }

    // ---- epilogue: C/D col = lane&15, row = (lane>>4)*4 + reg  [verified R2-R6] ----
    const int orow = rowbase + wv * 16 + kgrp * 4;
#pragma unroll
    for (int nt = 0; nt < 5; ++nt) {
        const int col = nt * 16 + l15;
        if (col < NTAGS) {
            const float bias = b_out[col];
#pragma unroll
            for (int i = 0; i < 4; ++i) {
                out[(size_t)(orow + i) * NTAGS + col] = acc[nt][i] + bias;
            }
        }
    }
}

extern "C" void kernel_launch(void* const* d_in, const int* in_sizes, int n_in,
                              void* d_out, int out_size, void* d_ws, size_t ws_size,
                              hipStream_t stream) {
    const float* out_char = (const float*)d_in[0];
    const float* out_word = (const float*)d_in[1];
    const int* word_idx = (const int*)d_in[2];
    const int* is_head = (const int*)d_in[3];
    const int* valid_mask = (const int*)d_in[4];
    const float* W_out = (const float*)d_in[5];
    const float* b_out = (const float*)d_in[6];
    float* out = (float*)d_out;
    __bf16* Wt = (__bf16*)d_ws;  // 80*1024*2 = 160 KB

    prep_w_kernel<<<HH / 64, 256, 0, stream>>>(W_out, Wt);

    const int rows = 16 * TT;  // B*T = 32768
    slu_main<<<rows / MROWS, THREADS, 0, stream>>>(out_char, out_word, word_idx, is_head,
                                                   valid_mask, Wt, b_out, out);
}

// Round 8
// 35.379 us; speedup vs baseline: 1.3040x; 1.3040x over previous
//
#include <hip/hip_runtime.h>
#include <hip/hip_bf16.h>

#define TT 2048
#define HH 1024
#define NTAGS 74
#define NPAD 80
#define CHK 64            // K elements per chunk
#define NCH (HH / CHK)    // 16 chunks
#define MROWS 64          // rows per block
#define THREADS 256

typedef __bf16 bf16x8 __attribute__((ext_vector_type(8)));
typedef float f32x4 __attribute__((ext_vector_type(4)));

// Transpose + convert W_out [1024][74] f32 -> Wt [80][1024] bf16 (pad cols 74..79 = 0)
__global__ __launch_bounds__(256) void prep_w_kernel(const float* __restrict__ W,
                                                     __bf16* __restrict__ Wt) {
    __shared__ float tile[64][80];
    const int k0 = blockIdx.x * 64;
    const int tid = threadIdx.x;
    for (int i = tid; i < 64 * NTAGS; i += 256) {
        int k = i / NTAGS, n = i - k * NTAGS;
        tile[k][n] = W[(k0 + k) * NTAGS + n];
    }
    __syncthreads();
    for (int i = tid; i < NPAD * 64; i += 256) {
        int n = i >> 6, kk = i & 63;
        float v = (n < NTAGS) ? tile[kk][n] : 0.0f;
        Wt[n * HH + k0 + kk] = (__bf16)v;
    }
}

// R8 = R5 (best known: 35.5 us) + ONE change: 2-chunk register-held prefetch.
// Block = 256 thr (4 waves), M=64 rows, grid 512. K chunks of 64; A triple-buffered
// (3x8KB) + W double-buffered (2x10KB) in LDS, XOR-swizzled (byte ^= (row&7)<<4).
// Loop: commit regsA(ch+1) -> shift B->A -> issue loads(ch+3)->regsB -> MFMA(ch)
// -> barrier. Each load now has TWO compute+barrier phases of slack (MLP x2).
__global__ __launch_bounds__(256, 2) void slu_main(const float* __restrict__ out_char,
                                                   const float* __restrict__ out_word,
                                                   const int* __restrict__ word_idx,
                                                   const int* __restrict__ is_head,
                                                   const int* __restrict__ valid_mask,
                                                   const __bf16* __restrict__ Wt,
                                                   const float* __restrict__ b_out,
                                                   float* __restrict__ out) {
    // LDS: A[3] @ 0 (3*8192), W[2] @ 24576 (2*10240) = 45056 B
    __shared__ __align__(16) char smem[45056];
    const int tid = threadIdx.x;
    const int wv = tid >> 6;
    const int lane = tid & 63;
    const int l15 = lane & 15;
    const int kgrp = lane >> 4;
    const int rowbase = blockIdx.x * MROWS;

    // ---- A staging (R5 map): thread covers row rloc=(tid>>2), k-sub q=(tid&3) ----
    const int rloc = tid >> 2;
    const int q = tid & 3;
    const int r = rowbase + rloc;
    const int bq = r >> 11;  // T = 2048
    const int widx = word_idx[r];
    const int val = valid_mask[r];
    const float rt = is_head[r] ? 0.88f : 0.70f;
    const float rate = val ? rt : 0.0f;
    const float crate = val ? (1.0f - rt) : 0.0f;
    const float* cptr = out_char + (size_t)r * HH + q * 16;
    const float* wptr = out_word + ((size_t)bq * TT + widx) * HH + q * 16;
    const int asw = (rloc & 7) << 4;
    const int awr0 = (rloc * 128 + q * 32) ^ asw;
    const int awr1 = (rloc * 128 + q * 32 + 16) ^ asw;

    // ---- W staging (R5 map): 640 16B-units/chunk; thread covers tid, tid+256, (tid<128)?tid+512 ----
    const int wn0 = tid >> 3, wsb = tid & 7;
    const __bf16* wgp0 = Wt + (size_t)wn0 * HH + wsb * 8;
    const __bf16* wgp1 = wgp0 + 32 * HH;
    const __bf16* wgp2 = wgp0 + 64 * HH;
    const int wsw = (wn0 & 7) << 4;
    const int wwr0 = (wn0 * 128 + wsb * 16) ^ wsw;
    const int wwr1 = ((wn0 + 32) * 128 + wsb * 16) ^ wsw;
    const int wwr2 = ((wn0 + 64) * 128 + wsb * 16) ^ wsw;
    const bool w3 = (tid < 128);

    // ---- fragment read offsets (swizzle matches writes; row&7 == l15&7 for A and W) ----
    const int fsw = (l15 & 7) << 4;
    const int arow = wv * 16 + l15;
    int aoff[2], woff[2][5];
#pragma unroll
    for (int s = 0; s < 2; ++s) {
        aoff[s] = (arow * 128 + s * 64 + kgrp * 16) ^ fsw;
#pragma unroll
        for (int nt = 0; nt < 5; ++nt)
            woff[s][nt] = ((nt * 16 + l15) * 128 + s * 64 + kgrp * 16) ^ fsw;
    }

    f32x4 acc[5];
#pragma unroll
    for (int nt = 0; nt < 5; ++nt) acc[nt] = (f32x4){0.f, 0.f, 0.f, 0.f};

    // two register-held chunk sets: A-set (committed next) and B-set (in flight)
    float4 acA[4], awA[4], acB[4], awB[4];
    bf16x8 wA0, wA1, wA2, wB0, wB1, wB2;

    // ---- prologue: stage chunk 0 directly; load ch1 -> set A; load ch2 -> set B ----
    {
        float4 c0[4], w0[4];
        if (val) {
#pragma unroll
            for (int i = 0; i < 4; ++i) {
                c0[i] = *(const float4*)(cptr + i * 4);
                w0[i] = *(const float4*)(wptr + i * 4);
            }
        }
        bf16x8 wr0 = *(const bf16x8*)(wgp0);
        bf16x8 wr1 = *(const bf16x8*)(wgp1);
        bf16x8 wr2 = w3 ? *(const bf16x8*)(wgp2) : (bf16x8)0;
        bf16x8 f0, f1;
        if (val) {
#pragma unroll
            for (int i = 0; i < 2; ++i) {
                f0[i * 4 + 0] = (__bf16)(w0[i].x * rate + c0[i].x * crate);
                f0[i * 4 + 1] = (__bf16)(w0[i].y * rate + c0[i].y * crate);
                f0[i * 4 + 2] = (__bf16)(w0[i].z * rate + c0[i].z * crate);
                f0[i * 4 + 3] = (__bf16)(w0[i].w * rate + c0[i].w * crate);
                f1[i * 4 + 0] = (__bf16)(w0[i + 2].x * rate + c0[i + 2].x * crate);
                f1[i * 4 + 1] = (__bf16)(w0[i + 2].y * rate + c0[i + 2].y * crate);
                f1[i * 4 + 2] = (__bf16)(w0[i + 2].z * rate + c0[i + 2].z * crate);
                f1[i * 4 + 3] = (__bf16)(w0[i + 2].w * rate + c0[i + 2].w * crate);
            }
        } else {
            f0 = (bf16x8)0; f1 = (bf16x8)0;
        }
        *(bf16x8*)(smem + awr0) = f0;
        *(bf16x8*)(smem + awr1) = f1;
        *(bf16x8*)(smem + 24576 + wwr0) = wr0;
        *(bf16x8*)(smem + 24576 + wwr1) = wr1;
        if (w3) *(bf16x8*)(smem + 24576 + wwr2) = wr2;
        // load chunk 1 -> set A
        if (val) {
#pragma unroll
            for (int i = 0; i < 4; ++i) {
                acA[i] = *(const float4*)(cptr + CHK + i * 4);
                awA[i] = *(const float4*)(wptr + CHK + i * 4);
            }
        }
        wA0 = *(const bf16x8*)(wgp0 + CHK);
        wA1 = *(const bf16x8*)(wgp1 + CHK);
        wA2 = w3 ? *(const bf16x8*)(wgp2 + CHK) : (bf16x8)0;
        // load chunk 2 -> set B
        if (val) {
#pragma unroll
            for (int i = 0; i < 4; ++i) {
                acB[i] = *(const float4*)(cptr + 2 * CHK + i * 4);
                awB[i] = *(const float4*)(wptr + 2 * CHK + i * 4);
            }
        }
        wB0 = *(const bf16x8*)(wgp0 + 2 * CHK);
        wB1 = *(const bf16x8*)(wgp1 + 2 * CHK);
        wB2 = w3 ? *(const bf16x8*)(wgp2 + 2 * CHK) : (bf16x8)0;
    }
    __syncthreads();

    // ---- main loop ----
    for (int ch = 0; ch < NCH; ++ch) {
        // 1) commit set A (chunk ch+1) to LDS
        if (ch + 1 < NCH) {
            char* An = smem + ((ch + 1) % 3) * 8192;
            char* Wn = smem + 24576 + ((ch + 1) & 1) * 10240;
            bf16x8 f0, f1;
            if (val) {
#pragma unroll
                for (int i = 0; i < 2; ++i) {
                    f0[i * 4 + 0] = (__bf16)(awA[i].x * rate + acA[i].x * crate);
                    f0[i * 4 + 1] = (__bf16)(awA[i].y * rate + acA[i].y * crate);
                    f0[i * 4 + 2] = (__bf16)(awA[i].z * rate + acA[i].z * crate);
                    f0[i * 4 + 3] = (__bf16)(awA[i].w * rate + acA[i].w * crate);
                    f1[i * 4 + 0] = (__bf16)(awA[i + 2].x * rate + acA[i + 2].x * crate);
                    f1[i * 4 + 1] = (__bf16)(awA[i + 2].y * rate + acA[i + 2].y * crate);
                    f1[i * 4 + 2] = (__bf16)(awA[i + 2].z * rate + acA[i + 2].z * crate);
                    f1[i * 4 + 3] = (__bf16)(awA[i + 2].w * rate + acA[i + 2].w * crate);
                }
            } else {
                f0 = (bf16x8)0; f1 = (bf16x8)0;
            }
            *(bf16x8*)(An + awr0) = f0;
            *(bf16x8*)(An + awr1) = f1;
            *(bf16x8*)(Wn + wwr0) = wA0;
            *(bf16x8*)(Wn + wwr1) = wA1;
            if (w3) *(bf16x8*)(Wn + wwr2) = wA2;
        }
        // 2) shift B -> A
#pragma unroll
        for (int i = 0; i < 4; ++i) { acA[i] = acB[i]; awA[i] = awB[i]; }
        wA0 = wB0; wA1 = wB1; wA2 = wB2;
        // 3) issue global loads for chunk ch+3 -> set B
        if (ch + 3 < NCH) {
            const int ko = (ch + 3) * CHK;
            if (val) {
#pragma unroll
                for (int i = 0; i < 4; ++i) {
                    acB[i] = *(const float4*)(cptr + ko + i * 4);
                    awB[i] = *(const float4*)(wptr + ko + i * 4);
                }
            }
            wB0 = *(const bf16x8*)(wgp0 + ko);
            wB1 = *(const bf16x8*)(wgp1 + ko);
            wB2 = w3 ? *(const bf16x8*)(wgp2 + ko) : (bf16x8)0;
        }
        // 4) compute chunk ch
        const char* Ab = smem + (ch % 3) * 8192;
        const char* Wb = smem + 24576 + (ch & 1) * 10240;
#pragma unroll
        for (int s = 0; s < 2; ++s) {
            bf16x8 a = *(const bf16x8*)(Ab + aoff[s]);
#pragma unroll
            for (int nt = 0; nt < 5; ++nt) {
                bf16x8 bw = *(const bf16x8*)(Wb + woff[s][nt]);
                acc[nt] = __builtin_amdgcn_mfma_f32_16x16x32_bf16(a, bw, acc[nt], 0, 0, 0);
            }
        }
        __syncthreads();
    }

    // ---- epilogue: C/D col = lane&15, row = (lane>>4)*4 + reg  [verified R2-R7] ----
    const int orow = rowbase + wv * 16 + kgrp * 4;
#pragma unroll
    for (int nt = 0; nt < 5; ++nt) {
        const int col = nt * 16 + l15;
        if (col < NTAGS) {
            const float bias = b_out[col];
#pragma unroll
            for (int i = 0; i < 4; ++i) {
                out[(size_t)(orow + i) * NTAGS + col] = acc[nt][i] + bias;
            }
        }
    }
}

extern "C" void kernel_launch(void* const* d_in, const int* in_sizes, int n_in,
                              void* d_out, int out_size, void* d_ws, size_t ws_size,
                              hipStream_t stream) {
    const float* out_char = (const float*)d_in[0];
    const float* out_word = (const float*)d_in[1];
    const int* word_idx = (const int*)d_in[2];
    const int* is_head = (const int*)d_in[3];
    const int* valid_mask = (const int*)d_in[4];
    const float* W_out = (const float*)d_in[5];
    const float* b_out = (const float*)d_in[6];
    float* out = (float*)d_out;
    __bf16* Wt = (__bf16*)d_ws;  // 80*1024*2 = 160 KB

    prep_w_kernel<<<HH / 64, 256, 0, stream>>>(W_out, Wt);

    const int rows = 16 * TT;  // B*T = 32768
    slu_main<<<rows / MROWS, THREADS, 0, stream>>>(out_char, out_word, word_idx, is_head,
                                                   valid_mask, Wt, b_out, out);
}